// Round 4
// baseline (228.474 us; speedup 1.0000x reference)
//
#include <hip/hip_runtime.h>
#include <math.h>

#define HH 160
#define WW 160
#define DD 160
#define VOL (HH*WW*DD)          // 4,096,000
#define KS 11
#define PAD 5
#define NBATCH 2
#define NTOT (NBATCH*VOL)
#define WCH 16                   // w-outputs per thread in k1 (10 chunks)
#define HCH 16                   // h-outputs per thread in k2 (10 chunks)

struct Wts { float w[KS]; };

__device__ __forceinline__ int mirror(int i, int n) {
    if (i < 0) i = -i;
    if (i >= n) i = 2*n - 2 - i;
    return i;
}

__device__ __forceinline__ float fastdiv(float a, float b) {
    return a * __builtin_amdgcn_rcpf(b);
}

__global__ void init_out(float* out) {
    if (threadIdx.x == 0 && blockIdx.x == 0) out[0] = 1.0f;
}

// k1: fused D-blur + W-blur. Thread fixes (b,h,d), walks a 16-wide w chunk.
// Per step: 11 contiguous-d taps of src/ref (mirrored offsets precomputed,
// loop-invariant) -> 5-channel D-blur in regs -> delay-line ring accumulators
// for the W-blur (static ring indices, no shifts). Writes B = W(D(chan)).
__global__ __launch_bounds__(256) void k1(const float* __restrict__ src,
                                          const float* __restrict__ ref,
                                          float* __restrict__ B, Wts wts) {
    // grid: NBATCH * (WW/WCH) * (HH*DD/256) = 2*10*100 = 2000
    const int colsBlocks = HH * DD / 256;            // 100
    int colblk = blockIdx.x % colsBlocks;
    int rest   = blockIdx.x / colsBlocks;
    int wch    = rest % (WW / WCH);
    int b      = rest / (WW / WCH);
    int col    = colblk * 256 + threadIdx.x;         // h*DD + d
    int h = col / DD, d = col % DD;
    const int w0 = wch * WCH;

    const float* sp = src + (size_t)b * VOL + (size_t)h * WW * DD;
    const float* rp = ref + (size_t)b * VOL + (size_t)h * WW * DD;
    float*       op = B   + (size_t)b * 5 * VOL + (size_t)h * WW * DD + d;

    int midx[KS];
#pragma unroll
    for (int k = 0; k < KS; ++k) midx[k] = mirror(d - PAD + k, DD);

    float acc[5][KS];
#pragma unroll
    for (int c = 0; c < 5; ++c)
#pragma unroll
        for (int s = 0; s < KS; ++s) acc[c][s] = 0.f;

    const int NSTEP = WCH + 2 * PAD;                 // 26
    for (int tb = 0; tb < 33; tb += 11) {
#pragma unroll
        for (int ts = 0; ts < 11; ++ts) {
            int t = tb + ts;
            if (t < NSTEP) {
                int wm   = mirror(w0 - PAD + t, WW); // tap w-position (uniform)
                int woff = wm * DD;
                // 5-channel D-blur at (h, wm, d)
                float mu1 = 0.f, mu2 = 0.f, m11 = 0.f, m22 = 0.f, m12 = 0.f;
#pragma unroll
                for (int k = 0; k < KS; ++k) {
                    float s = sp[woff + midx[k]];
                    float r = rp[woff + midx[k]];
                    float wt = wts.w[k];
                    float p = wt * s, q = wt * r;
                    mu1 += p; mu2 += q;
                    m11 = fmaf(p, s, m11);
                    m22 = fmaf(q, r, m22);
                    m12 = fmaf(p, r, m12);
                }
                float v[5] = {mu1, mu2, m11, m22, m12};
                // delay-line: contribute to the 11 pending w-outputs
#pragma unroll
                for (int m = 0; m < 11; ++m) {
                    int slot = (ts + m) % 11;        // static after unroll
                    float wt = wts.w[10 - m];
#pragma unroll
                    for (int c = 0; c < 5; ++c)
                        acc[c][slot] = fmaf(wt, v[c], acc[c][slot]);
                }
                // emit slot ts: output w index o = w0 - 10 + t
                int o = w0 - 10 + t;
                if (t >= 10) {
#pragma unroll
                    for (int c = 0; c < 5; ++c)
                        op[(size_t)c * VOL + (size_t)o * DD] = acc[c][ts];
                }
#pragma unroll
                for (int c = 0; c < 5; ++c) acc[c][ts] = 0.f;
            }
        }
    }
}

// k2: H-blur of the 5 B-channels via the same delay-line, SSIM at emission,
// block reduction, one atomic per block.
__global__ __launch_bounds__(256) void k2(const float* __restrict__ B,
                                          float* __restrict__ out,
                                          Wts wts, float scale) {
    // grid: NBATCH * (HH/HCH) * (WW*DD/256) = 2*10*100 = 2000
    const int colsBlocks = WW * DD / 256;            // 100
    int colblk = blockIdx.x % colsBlocks;
    int rest   = blockIdx.x / colsBlocks;
    int hch    = rest % (HH / HCH);
    int b      = rest / (HH / HCH);
    int col    = colblk * 256 + threadIdx.x;         // w*DD + d
    const int h0 = hch * HCH;
    const float* p = B + (size_t)b * 5 * VOL + col;
    const size_t HS = (size_t)WW * DD;

    float acc[5][KS];
#pragma unroll
    for (int c = 0; c < 5; ++c)
#pragma unroll
        for (int s = 0; s < KS; ++s) acc[c][s] = 0.f;

    float ssum = 0.f;
    const int NSTEP = HCH + 2 * PAD;                 // 26
    for (int tb = 0; tb < 33; tb += 11) {
#pragma unroll
        for (int ts = 0; ts < 11; ++ts) {
            int t = tb + ts;
            if (t < NSTEP) {
                int hm = mirror(h0 - PAD + t, HH);
                size_t off = (size_t)hm * HS;
                float v0 = p[off];
                float v1 = p[off + 1 * (size_t)VOL];
                float v2 = p[off + 2 * (size_t)VOL];
                float v3 = p[off + 3 * (size_t)VOL];
                float v4 = p[off + 4 * (size_t)VOL];
#pragma unroll
                for (int m = 0; m < 11; ++m) {
                    int slot = (ts + m) % 11;
                    float wt = wts.w[10 - m];
                    acc[0][slot] = fmaf(wt, v0, acc[0][slot]);
                    acc[1][slot] = fmaf(wt, v1, acc[1][slot]);
                    acc[2][slot] = fmaf(wt, v2, acc[2][slot]);
                    acc[3][slot] = fmaf(wt, v3, acc[3][slot]);
                    acc[4][slot] = fmaf(wt, v4, acc[4][slot]);
                }
                if (t >= 10) {
                    float mu1 = acc[0][ts], mu2 = acc[1][ts];
                    float m11 = acc[2][ts], m22 = acc[3][ts], m12 = acc[4][ts];
                    float mu1sq = mu1 * mu1, mu2sq = mu2 * mu2, mu12 = mu1 * mu2;
                    float s1 = m11 - mu1sq, s2 = m22 - mu2sq, s12 = m12 - mu12;
                    const float C1 = 1e-4f, C2 = 9e-4f;
                    float num = (2.f * mu12 + C1) * (2.f * s12 + C2);
                    float den = (mu1sq + mu2sq + C1) * (s1 + s2 + C2);
                    ssum += fastdiv(num, den + 1e-12f);
                }
#pragma unroll
                for (int c = 0; c < 5; ++c) acc[c][ts] = 0.f;
            }
        }
    }

#pragma unroll
    for (int off = 32; off > 0; off >>= 1)
        ssum += __shfl_down(ssum, off, 64);
    __shared__ float lsum[4];
    int lane = threadIdx.x & 63, wid = threadIdx.x >> 6;
    if (lane == 0) lsum[wid] = ssum;
    __syncthreads();
    if (threadIdx.x == 0) {
        float s = lsum[0] + lsum[1] + lsum[2] + lsum[3];
        atomicAdd(out, -s * scale);
    }
}

// Fallback: brute-force 11^3 taps per voxel (only if ws too small).
__global__ void brute(const float* __restrict__ src, const float* __restrict__ ref,
                      float* __restrict__ out, Wts wts, float scale) {
    long gi = (long)blockIdx.x * blockDim.x + threadIdx.x;
    float ssim = 0.f;
    if (gi < NTOT) {
        int v = (int)(gi % VOL);
        int b = (int)(gi / VOL);
        int d = v % DD;
        int w = (v / DD) % WW;
        int h = v / (DD * WW);
        const float* sp = src + (long)b * VOL;
        const float* rp = ref + (long)b * VOL;
        float a0 = 0.f, a1 = 0.f, a2 = 0.f, a3 = 0.f, a4 = 0.f;
        for (int i = 0; i < KS; ++i) {
            int hm = mirror(h + i - PAD, HH);
            float wx = wts.w[i];
            for (int j = 0; j < KS; ++j) {
                int wm = mirror(w + j - PAD, WW);
                float wxy = wx * wts.w[j];
                const float* sr = sp + ((long)hm * WW + wm) * DD;
                const float* rr = rp + ((long)hm * WW + wm) * DD;
                for (int k = 0; k < KS; ++k) {
                    int dm = mirror(d + k - PAD, DD);
                    float wt = wxy * wts.w[k];
                    float s = sr[dm], r = rr[dm];
                    a0 += wt * s; a1 += wt * r; a2 += wt * s * s;
                    a3 += wt * r * r; a4 += wt * s * r;
                }
            }
        }
        float mu1sq = a0 * a0, mu2sq = a1 * a1, mu12 = a0 * a1;
        float s1 = a2 - mu1sq, s2 = a3 - mu2sq, s12 = a4 - mu12;
        const float C1 = 1e-4f, C2 = 9e-4f;
        float num = (2.f * mu12 + C1) * (2.f * s12 + C2);
        float den = (mu1sq + mu2sq + C1) * (s1 + s2 + C2);
        ssim = num / (den + 1e-12f);
    }
#pragma unroll
    for (int off = 32; off > 0; off >>= 1)
        ssim += __shfl_down(ssim, off, 64);
    __shared__ float lsum[4];
    int lane = threadIdx.x & 63, wid = threadIdx.x >> 6;
    if (lane == 0) lsum[wid] = ssim;
    __syncthreads();
    if (threadIdx.x == 0) {
        float s = lsum[0] + lsum[1] + lsum[2] + lsum[3];
        atomicAdd(out, -s * scale);
    }
}

extern "C" void kernel_launch(void* const* d_in, const int* in_sizes, int n_in,
                              void* d_out, int out_size, void* d_ws, size_t ws_size,
                              hipStream_t stream) {
    const float* src = (const float*)d_in[0];
    const float* ref = (const float*)d_in[1];
    float* out = (float*)d_out;

    Wts wts;
    {
        double g[KS], s = 0.0;
        for (int i = 0; i < KS; ++i) {
            double a = (double)i - (KS - 1) / 2.0;
            g[i] = exp(-(a * a) / (2.0 * 1.5 * 1.5));
            s += g[i];
        }
        for (int i = 0; i < KS; ++i) wts.w[i] = (float)(g[i] / s);
    }

    const float scale = 1.0f / (float)NTOT;
    const size_t need = (size_t)NBATCH * 5 * VOL * sizeof(float);  // 163.84 MB

    init_out<<<1, 64, 0, stream>>>(out);

    if (ws_size >= need) {
        float* B = (float*)d_ws;
        const int g1 = NBATCH * (WW / WCH) * (HH * DD / 256);  // 2000
        const int g2 = NBATCH * (HH / HCH) * (WW * DD / 256);  // 2000
        k1<<<g1, 256, 0, stream>>>(src, ref, B, wts);
        k2<<<g2, 256, 0, stream>>>(B, out, wts, scale);
    } else {
        const int BLK = 256;
        const long g = (NTOT + BLK - 1) / BLK;
        brute<<<(int)g, BLK, 0, stream>>>(src, ref, out, wts, scale);
    }
}